// Round 4
// baseline (243.326 us; speedup 1.0000x reference)
//
#include <hip/hip_runtime.h>

// Problem constants (reference: B=4, L=8192, D=1024, K=7)
constexpr int B = 4;
constexpr int L = 8192;
constexpr int D = 1024;
constexpr int K = 7;
constexpr int HALF = K / 2;     // 3
constexpr int T = 32;           // l-rows per thread (per block)
constexpr int C = 8;            // chunk size == prefetch depth
constexpr int WIN = C + K - 1;  // 14-row register sliding window

typedef float v4f __attribute__((ext_vector_type(4)));

// Block = 256 threads x 4 channels = all D=1024, T=32 consecutive l-rows.
// Register sliding window X[14] covers rows [lc-6, lc+7]; while computing
// chunk c's 8 outputs, the next chunk's 8 row-loads (Y) are already in
// flight -> 8 independent loads/wave hide HBM latency; halo read
// amplification is only 6/32 = 19% (vs 75% at T=8).
__global__ __launch_bounds__(256, 2)
void dynconv_kernel(const float* __restrict__ x,
                    const float* __restrict__ sb,
                    const float* __restrict__ w,
                    const float* __restrict__ bias,
                    float* __restrict__ out)
{
    __shared__ float sh_mask[T];

    const int nt  = L / T;                  // 256 tiles per batch
    const int b   = blockIdx.x / nt;
    const int l0  = (blockIdx.x % nt) * T;
    const int tid = threadIdx.x;

    // ---- per-tile mask (box-filter of boundaries, width 7) ----
    if (tid < T) {
        const int l = l0 + tid;
        float cnt = 0.f;
        #pragma unroll
        for (int j = -HALF; j <= HALF; ++j) {
            const int p = l + j;
            if (p >= 0 && p < L) cnt += sb[(size_t)b * L + p];
        }
        sh_mask[tid] = exp2f(-cnt);         // 0.5 ** count
    }

    const int d0 = tid * 4;
    const float* xb = x + (size_t)b * L * D + d0;
    float*       ob = out + ((size_t)b * L + (size_t)l0) * D + d0;

    // ---- weights: 28 contiguous floats (4 ch x K) per thread ----
    union { v4f q[7]; float f[28]; } wu;
    {
        const v4f* wp = (const v4f*)(w + (size_t)d0 * K);   // 112B-aligned
        #pragma unroll
        for (int j = 0; j < 7; ++j) wu.q[j] = wp[j];
    }
    const v4f bv = *(const v4f*)(bias + d0);

    // ---- window prologue: X[j] = row l0-6+j, j=0..13 ----
    v4f X[WIN];
    #pragma unroll
    for (int j = 0; j < WIN; ++j) {
        const int l = l0 - (K - 1) + j;
        X[j] = (l >= 0) ? *(const v4f*)(xb + (size_t)l * D) : (v4f)(0.f);
    }

    __syncthreads();

    for (int c = 0; c < T / C; ++c) {
        // issue next chunk's loads first (rows l0 + c*C + 8 .. +15)
        v4f Y[C];
        if (c < T / C - 1) {
            #pragma unroll
            for (int j = 0; j < C; ++j)
                Y[j] = *(const v4f*)(xb + (size_t)(l0 + c * C + C + j) * D);
        }

        // compute current chunk from X (rows lc-6 .. lc+7)
        #pragma unroll
        for (int t = 0; t < C; ++t) {
            const float m = sh_mask[c * C + t];
            v4f acc = bv;
            #pragma unroll
            for (int k = 0; k < K; ++k) {
                v4f wk = { wu.f[0 * K + k], wu.f[1 * K + k],
                           wu.f[2 * K + k], wu.f[3 * K + k] };
                acc += wk * X[t + k];
            }
            acc *= m;
            __builtin_nontemporal_store(acc, (v4f*)(ob + (size_t)(c * C + t) * D));
        }

        // slide window by C
        if (c < T / C - 1) {
            #pragma unroll
            for (int j = 0; j < K - 1; ++j) X[j] = X[j + C];
            #pragma unroll
            for (int j = 0; j < C; ++j)     X[K - 1 + j] = Y[j];
        }
    }
}

extern "C" void kernel_launch(void* const* d_in, const int* in_sizes, int n_in,
                              void* d_out, int out_size, void* d_ws, size_t ws_size,
                              hipStream_t stream)
{
    const float* x    = (const float*)d_in[0];  // (B, L, D)
    const float* sb   = (const float*)d_in[1];  // (B, L)
    const float* w    = (const float*)d_in[2];  // (D, 1, K)
    const float* bias = (const float*)d_in[3];  // (D,)
    float* out = (float*)d_out;                 // (B, L, D)

    const int blocks = B * (L / T);             // 1024
    dynconv_kernel<<<blocks, 256, 0, stream>>>(x, sb, w, bias, out);
}